// Round 4
// baseline (121.622 us; speedup 1.0000x reference)
//
#include <hip/hip_runtime.h>

// Problem constants (fixed by the reference)
#define NB   8
#define C    128
#define H    112
#define W    112
#define HW   (H * W)
#define HO   56
#define WO   56
#define KK   9      // 3x3 = 9 sigma channels
#define WAVES 16
#define PPW  4                   // channel-pairs per wave
#define WPW  (PPW * 81)          // packed v2f weights per wave = 324

typedef float v2f __attribute__((ext_vector_type(2)));

// Packed fp32 fma -> v_pk_fma_f32 on gfx950 (VOP3P); falls back to 2x v_fma.
__device__ inline v2f pkfma(v2f a, v2f b, v2f c) {
    return __builtin_elementwise_fma(a, b, c);
}

// ---------------------------------------------------------------------------
// Single fused kernel: PASA downsample, streaming x, 2 blocks/CU, weight
// prep folded in as per-wave LDS staging.
//
// Design lineage (rocprof-driven):
//  - r2: register-resident x + 80 KB LDS -> compiler targeted 32 waves/CU ->
//        64-VGPR cap -> ~21 MB scratch spill, 45 us. Lesson: at 2 blocks/CU
//        the body must LIVE in <=64 VGPRs by design.
//  - r3: streaming Phase A (x re-read in Phase B from L2), 2 blocks/CU:
//        106.7 us total, main off the top-5 (<~15 us vs 10.3 us BW floor).
//  - r4 (this): fold the weight prep back in, now that the body is small.
//        Each wave stages its own 4 channel-pairs (324 v2f, BN scale folded
//        via rsqrtf) into a private LDS slab. Intra-wave produce/consume ->
//        NO extra __syncthreads; staging global reads overlap the x-load
//        stream. Phase A weight reads are wave-uniform ds_read broadcasts
//        (conflict-free; LDS pipe is otherwise idle). BN shift computed by
//        the reduce threads. Removes the serialized prep dispatch (~4-5 us).
//
// LDS: 41472 (wlds) + 36864 (part) + 2052 (sig) = 80388 -> 80896 alloc;
// x2 blocks = 161792 <= 163840 -> 2 blocks/CU preserved.
// Grid 448 @ 2/CU, XCD swizzle: bid%8 = n -> image n resident on one XCD's
// L2 (seam-row reuse + Phase B re-reads are L2 hits).
// ---------------------------------------------------------------------------
__global__ __launch_bounds__(1024, 8)   // 8 waves/EU = 2 blocks/CU, VGPR cap 64
void pasa_main(const float* __restrict__ x,
               const float* __restrict__ cw,
               const float* __restrict__ bw,
               const float* __restrict__ bb,
               const float* __restrict__ bm,
               const float* __restrict__ bv,
               float* __restrict__ out) {
    __shared__ v2f   wlds[WAVES][WPW];        // 41472 B packed scaled weights
    __shared__ float part[WAVES * KK * 64];   // 36864 B
    __shared__ float sig[KK * 57];            // 2052 B, padded row stride

    const int bid  = blockIdx.x;
    const int n    = bid & 7;
    const int ho   = bid >> 3;
    const int tid  = threadIdx.x;
    const int lane = tid & 63;
    const int wv   = __builtin_amdgcn_readfirstlane(tid >> 6);  // wave-uniform
    const int wo   = lane < WO ? lane : (WO - 1);               // clamp tail

    // Reflection-resolved source rows (top reflect only: -1 -> 1).
    const int r0 = (ho == 0) ? 1 : (2 * ho - 1);
    const int r1 = 2 * ho;
    const int r2 = 2 * ho + 1;

    const float* xn = x + (size_t)n * C * HW + 2 * wo;
    const int p0 = wv * PPW;   // first channel-pair of this wave

    // ---- Per-wave weight staging (no barrier: intra-wave produce/consume).
    // wlds[wv][p*81 + kh*27 + k*3 + kw] = {cw_a, cw_b} * scale[k]
    for (int i = lane; i < WPW; i += 64) {
        const int p   = i / 81;
        const int rem = i % 81;
        const int kh  = rem / 27;
        const int rr  = rem % 27;
        const int k   = rr / 3;
        const int kw  = rr % 3;
        const float scale = bw[k] * rsqrtf(bv[k] + 1e-5f);
        const int ca = 2 * (p0 + p);
        v2f w2;
        w2.x = cw[((k * C + ca)     * 3 + kh) * 3 + kw] * scale;
        w2.y = cw[((k * C + ca + 1) * 3 + kh) * 3 + kw] * scale;
        wlds[wv][i] = w2;
    }

    // ---- Phase A: streamed partial sigma over the 4 channel pairs ---------
    v2f acc[KK];
#pragma unroll
    for (int k = 0; k < KK; ++k) acc[k] = (v2f){0.0f, 0.0f};

#pragma unroll 2
    for (int p = 0; p < PPW; ++p) {
        const float* xa = xn + (size_t)(2 * (p0 + p)) * HW;
        const float* xb = xa + HW;
        v2f rowa[3], rowb[3];
        rowa[0] = *(const v2f*)(xa + r0 * W);
        rowa[1] = *(const v2f*)(xa + r1 * W);
        rowa[2] = *(const v2f*)(xa + r2 * W);
        rowb[0] = *(const v2f*)(xb + r0 * W);
        rowb[1] = *(const v2f*)(xb + r1 * W);
        rowb[2] = *(const v2f*)(xb + r2 * W);
#pragma unroll
        for (int kh = 0; kh < 3; ++kh) {
            v2f t1 = { rowa[kh].x, rowb[kh].x };
            v2f t2 = { rowa[kh].y, rowb[kh].y };
            v2f t0;
            t0.x = __shfl_up(t2.x, 1);   // lane0 keeps own = reflect(-1)=col1
            t0.y = __shfl_up(t2.y, 1);
            const v2f* wr = &wlds[wv][p * 81 + kh * 27];  // wave-uniform bcast
#pragma unroll
            for (int k = 0; k < KK; ++k)
                acc[k] = pkfma(t2, wr[3 * k + 2],
                          pkfma(t1, wr[3 * k + 1],
                          pkfma(t0, wr[3 * k + 0], acc[k])));
        }
    }

#pragma unroll
    for (int k = 0; k < KK; ++k)
        part[(wv * KK + k) * 64 + lane] = acc[k].x + acc[k].y;
    __syncthreads();

    // ---- Cross-wave reduce + BN shift + clamp -----------------------------
    if (tid < KK * WO) {
        const int k  = tid / WO;
        const int w_ = tid % WO;
        float s = 0.0f;
#pragma unroll
        for (int w2 = 0; w2 < WAVES; ++w2) s += part[(w2 * KK + k) * 64 + w_];
        const float scale = bw[k] * rsqrtf(bv[k] + 1e-5f);
        s += bb[k] - bm[k] * scale;   // shift (scale already folded in weights)
        s = fmaxf(s, 1e-4f);
        sig[k * 57 + w_] = s;
    }
    __syncthreads();

    // ---- Normalize into registers (per-lane, lane = wo) -------------------
    float sg[KK];
    float tot = 0.0f;
#pragma unroll
    for (int k = 0; k < KK; ++k) { sg[k] = sig[k * 57 + wo]; tot += sg[k]; }
    const float inv = 1.0f / tot;
#pragma unroll
    for (int k = 0; k < KK; ++k) sg[k] *= inv;

    // ---- Phase B: re-read x from L2, apply adaptive filter, NT store ------
    float* on = out + ((size_t)n * C) * (HO * WO) + (size_t)ho * WO + lane;
#pragma unroll 2
    for (int p = 0; p < PPW; ++p) {
        const float* xa = xn + (size_t)(2 * (p0 + p)) * HW;
        const float* xb = xa + HW;
        v2f o = (v2f){0.0f, 0.0f};
#pragma unroll
        for (int kh = 0; kh < 3; ++kh) {
            const int rr = (kh == 0) ? r0 : (kh == 1) ? r1 : r2;
            v2f a = *(const v2f*)(xa + rr * W);
            v2f b = *(const v2f*)(xb + rr * W);
            v2f t1 = { a.x, b.x };
            v2f t2 = { a.y, b.y };
            v2f t0;
            t0.x = __shfl_up(t2.x, 1);
            t0.y = __shfl_up(t2.y, 1);
            v2f s0 = { sg[kh * 3 + 0], sg[kh * 3 + 0] };
            v2f s1 = { sg[kh * 3 + 1], sg[kh * 3 + 1] };
            v2f s2 = { sg[kh * 3 + 2], sg[kh * 3 + 2] };
            o = pkfma(t2, s2, pkfma(t1, s1, pkfma(t0, s0, o)));
        }
        if (lane < WO) {
            const int ci = 2 * (p0 + p);
            // Output is never re-read: keep it out of L2 (seam-row reuse).
            __builtin_nontemporal_store(o.x, on + (size_t)ci * (HO * WO));
            __builtin_nontemporal_store(o.y, on + (size_t)(ci + 1) * (HO * WO));
        }
    }
}

extern "C" void kernel_launch(void* const* d_in, const int* in_sizes, int n_in,
                              void* d_out, int out_size, void* d_ws, size_t ws_size,
                              hipStream_t stream) {
    const float* x   = (const float*)d_in[0];
    const float* cw  = (const float*)d_in[1];
    const float* bw  = (const float*)d_in[2];
    const float* bb  = (const float*)d_in[3];
    const float* bm  = (const float*)d_in[4];
    const float* bv  = (const float*)d_in[5];
    float* out = (float*)d_out;
    (void)d_ws; (void)ws_size;

    // Single launch: weight prep folded into pasa_main (per-wave LDS staging).
    pasa_main<<<NB * HO, 1024, 0, stream>>>(x, cw, bw, bb, bm, bv, out);
}

// Round 5
// 112.474 us; speedup vs baseline: 1.0813x; 1.0813x over previous
//
#include <hip/hip_runtime.h>

// Problem constants (fixed by the reference)
#define NB   8
#define C    128
#define H    112
#define W    112
#define HW   (H * W)
#define HO   56
#define WO   56
#define KK   9      // 3x3 = 9 sigma channels
#define WAVES 16
#define CPW  8      // channels per wave

typedef float v2f __attribute__((ext_vector_type(2)));

// ---------------------------------------------------------------------------
// Single kernel, zero prep. Design lineage (rocprof-driven):
//  - r2/r4 lesson: __launch_bounds__(1024,w) caps VGPR at 256/w. (1024,8)->32
//    caused 10-21 MB of scratch spill both times something extra touched
//    VGPRs. LDS-staged weights cost VGPRs (ds_read results + staging temps).
//  - r3 (106.7us, best): streaming x, weights via WAVE-UNIFORM global pointer
//    -> s_load into SGPRs, zero VGPR cost. But needed a serialized prep
//    launch to pre-scale/pack the weights.
//  - r5 (this): kill prep WITHOUT touching VGPR pressure:
//      * Phase A reads RAW cw, k-outer so each (channel,k)'s 9 taps are
//        contiguous -> batched s_load, SGPRs only.
//      * BN scale folds into the cross-wave reduce (s = scale*sum + shift),
//        one FMA per (k,wo) thread -- mathematically identical.
//      * Scalar acc[9] (channel-pair v2f packing existed only for prepacked
//        weights) -> ~9 persistent VGPRs, body ~40 total.
//      * __launch_bounds__(1024,4) -> cap 64, no spill; at <=64 VGPR and
//        39 KB LDS the HW still co-schedules 2 blocks/CU (32 waves).
// Grid 448, XCD swizzle: bid%8 = n -> image n resident on one XCD's L2
// (seam rows 2ho+1 = 2(ho+1)-1 and Phase B re-reads are L2 hits).
// Phase B re-reads x from L2; NT stores keep output from evicting it.
// ---------------------------------------------------------------------------
__global__ __launch_bounds__(1024, 4)   // VGPR cap 64; body ~40 -> no spill
void pasa_main(const float* __restrict__ x,
               const float* __restrict__ cw,
               const float* __restrict__ bw,
               const float* __restrict__ bb,
               const float* __restrict__ bm,
               const float* __restrict__ bv,
               float* __restrict__ out) {
    __shared__ float part[WAVES * KK * 64];   // 36864 B
    __shared__ float sig[KK * 57];            // 2052 B, padded row stride

    const int bid  = blockIdx.x;
    const int n    = bid & 7;
    const int ho   = bid >> 3;
    const int tid  = threadIdx.x;
    const int lane = tid & 63;
    const int wv   = __builtin_amdgcn_readfirstlane(tid >> 6);  // wave-uniform
    const int wo   = lane < WO ? lane : (WO - 1);               // clamp tail

    // Reflection-resolved source rows (top reflect only: -1 -> 1).
    const int r0 = (ho == 0) ? 1 : (2 * ho - 1);
    const int r1 = 2 * ho;
    const int r2 = 2 * ho + 1;

    const float* xn = x + (size_t)n * C * HW + 2 * wo;
    const int c0 = wv * CPW;   // first channel of this wave

    // ---- Phase A: partial sigma over this wave's 8 channels ---------------
    // acc[k] accumulates the RAW conv (no BN scale); scale applied in reduce.
    float acc[KK];
#pragma unroll
    for (int k = 0; k < KK; ++k) acc[k] = 0.0f;

#pragma unroll 2
    for (int c = 0; c < CPW; ++c) {
        const float* xc = xn + (size_t)(c0 + c) * HW;
        v2f ra = *(const v2f*)(xc + r0 * W);
        v2f rb = *(const v2f*)(xc + r1 * W);
        v2f rc = *(const v2f*)(xc + r2 * W);
        // t1 = col 2wo, t2 = col 2wo+1, t0 = col 2wo-1 (lane0: keeps own t2
        // = col 1 = reflect(-1)).
        float t1[3] = { ra.x, rb.x, rc.x };
        float t2[3] = { ra.y, rb.y, rc.y };
        float t0[3];
#pragma unroll
        for (int kh = 0; kh < 3; ++kh) t0[kh] = __shfl_up(t2[kh], 1);

        // Wave-uniform raw weights: cw[((k*C + c)*3+kh)*3+kw]; k-outer so the
        // 9 taps of (c,k) are contiguous -> batched s_load into SGPRs.
        const float* wc = cw + (size_t)(c0 + c) * 9;
#pragma unroll
        for (int k = 0; k < KK; ++k) {
            const float* w = wc + (size_t)k * (C * 9);
            float a = acc[k];
#pragma unroll
            for (int kh = 0; kh < 3; ++kh)
                a = fmaf(t0[kh], w[kh * 3 + 0],
                    fmaf(t1[kh], w[kh * 3 + 1],
                    fmaf(t2[kh], w[kh * 3 + 2], a)));
            acc[k] = a;
        }
    }

#pragma unroll
    for (int k = 0; k < KK; ++k)
        part[(wv * KK + k) * 64 + lane] = acc[k];
    __syncthreads();

    // ---- Cross-wave reduce + BN scale/shift + clamp -----------------------
    if (tid < KK * WO) {
        const int k  = tid / WO;
        const int w_ = tid % WO;
        float s = 0.0f;
#pragma unroll
        for (int w2 = 0; w2 < WAVES; ++w2) s += part[(w2 * KK + k) * 64 + w_];
        const float scale = bw[k] * rsqrtf(bv[k] + 1e-5f);
        const float shift = bb[k] - bm[k] * scale;
        s = fmaf(scale, s, shift);
        s = fmaxf(s, 1e-4f);
        sig[k * 57 + w_] = s;
    }
    __syncthreads();

    // ---- Normalize into registers (per-lane, lane = wo) -------------------
    float sg[KK];
    float tot = 0.0f;
#pragma unroll
    for (int k = 0; k < KK; ++k) { sg[k] = sig[k * 57 + wo]; tot += sg[k]; }
    const float inv = 1.0f / tot;
#pragma unroll
    for (int k = 0; k < KK; ++k) sg[k] *= inv;

    // ---- Phase B: re-read x from L2, apply adaptive filter, NT store ------
    float* on = out + ((size_t)n * C) * (HO * WO) + (size_t)ho * WO + lane;
#pragma unroll 2
    for (int c = 0; c < CPW; ++c) {
        const float* xc = xn + (size_t)(c0 + c) * HW;
        v2f ra = *(const v2f*)(xc + r0 * W);
        v2f rb = *(const v2f*)(xc + r1 * W);
        v2f rc = *(const v2f*)(xc + r2 * W);
        float t1[3] = { ra.x, rb.x, rc.x };
        float t2[3] = { ra.y, rb.y, rc.y };
        float o = 0.0f;
#pragma unroll
        for (int kh = 0; kh < 3; ++kh) {
            float t0 = __shfl_up(t2[kh], 1);
            o = fmaf(t0,     sg[kh * 3 + 0],
                fmaf(t1[kh], sg[kh * 3 + 1],
                fmaf(t2[kh], sg[kh * 3 + 2], o)));
        }
        if (lane < WO) {
            // Output is never re-read: keep it out of L2 (seam-row reuse).
            __builtin_nontemporal_store(o, on + (size_t)(c0 + c) * (HO * WO));
        }
    }
}

extern "C" void kernel_launch(void* const* d_in, const int* in_sizes, int n_in,
                              void* d_out, int out_size, void* d_ws, size_t ws_size,
                              hipStream_t stream) {
    const float* x   = (const float*)d_in[0];
    const float* cw  = (const float*)d_in[1];
    const float* bw  = (const float*)d_in[2];
    const float* bb  = (const float*)d_in[3];
    const float* bm  = (const float*)d_in[4];
    const float* bv  = (const float*)d_in[5];
    float* out = (float*)d_out;
    (void)d_ws; (void)ws_size;

    // Single launch: raw weights consumed directly (s_load/SGPR path);
    // BN scale/shift folded into the reduce. No prep kernel.
    pasa_main<<<NB * HO, 1024, 0, stream>>>(x, cw, bw, bb, bm, bv, out);
}

// Round 6
// 109.031 us; speedup vs baseline: 1.1155x; 1.0316x over previous
//
#include <hip/hip_runtime.h>

// Problem constants (fixed by the reference)
#define NB   8
#define C    128
#define H    112
#define W    112
#define HW   (H * W)
#define HO   56
#define WO   56
#define KK   9      // 3x3 = 9 sigma channels
#define WAVES 16
#define PPW  4                   // channel-pairs per wave
#define NPAIR (C / 2)            // 64 channel pairs
#define WPK_ELEMS (NPAIR * 81)   // float2 count: [cip][kh][k*3+kw]
#define SHIFT_OFF (WPK_ELEMS * 2)  // float offset of shift[9] in ws

typedef float v2f __attribute__((ext_vector_type(2)));

// Packed fp32 fma -> v_pk_fma_f32 on gfx950 (VOP3P); falls back to 2x v_fma.
__device__ inline v2f pkfma(v2f a, v2f b, v2f c) {
    return __builtin_elementwise_fma(a, b, c);
}

// ---------------------------------------------------------------------------
// Kernel 0: weights -> d_ws as channel-PAIR packed float2, BN scale folded.
// Kept as a separate tiny launch: every prep-elimination attempt lost more
// than the ~4 us it costs (r2/r4: LDS-staged weights -> VGPR spill, 10-21 MB
// scratch; r5: raw k-outer weights -> 72 scattered s_load batches per wave,
// lgkmcnt serialization + 2x scalar VALU, main +11 us).
// ---------------------------------------------------------------------------
__global__ void pasa_prep(const float* __restrict__ cw,
                          const float* __restrict__ bw,
                          const float* __restrict__ bb,
                          const float* __restrict__ bm,
                          const float* __restrict__ bv,
                          float* __restrict__ ws) {
    int idx = blockIdx.x * 256 + threadIdx.x;
    if (idx < WPK_ELEMS) {
        int cip = idx / 81;
        int rem = idx % 81;
        int kh = rem / 27;
        int r2 = rem % 27;
        int k  = r2 / 3;
        int kw = r2 % 3;
        float scale = bw[k] * rsqrtf(bv[k] + 1e-5f);
        int ca = 2 * cip, cb = 2 * cip + 1;
        ws[2 * idx + 0] = cw[((k * C + ca) * 3 + kh) * 3 + kw] * scale;
        ws[2 * idx + 1] = cw[((k * C + cb) * 3 + kh) * 3 + kw] * scale;
    } else if (idx < WPK_ELEMS + KK) {
        int k = idx - WPK_ELEMS;
        float scale = bw[k] * rsqrtf(bv[k] + 1e-5f);
        ws[SHIFT_OFF + k] = bb[k] - bm[k] * scale;
    }
}

// ---------------------------------------------------------------------------
// Kernel 1: fused PASA downsample, streaming x, 2 blocks/CU.
// EXACTLY the round-3 winner (106.7 us) with ONE change: launch bounds
// (1024,8) -> (1024,4). r4's counters proved (1024,w) caps VGPR at 256/w,
// so r3 ran under a 32-VGPR cap with a ~45-50 live-reg body (mild spill /
// remat). Cap 64 removes that while keeping the same co-residency: 64 VGPR
// -> 32 waves/CU = 2 x 16-wave blocks; LDS 39 KB x2 <= 160 KB.
//
// Structure: Phase A streams channel pairs (unroll 2), weights via
// wave-uniform packed ws pointer -> batched s_load into SGPRs (zero VGPR
// cost); cross-wave LDS reduce + shift + clamp; Phase B re-reads x from L2
// (lines just fetched; XCD swizzle bid%8=n keeps image n on one XCD's L2)
// and NT-stores the output so it never evicts the reused seam rows.
// ---------------------------------------------------------------------------
__global__ __launch_bounds__(1024, 4)   // VGPR cap 64; body ~50 -> no spill
void pasa_main(const float* __restrict__ x,
               const v2f* __restrict__ wpk,
               const float* __restrict__ shift,
               float* __restrict__ out) {
    __shared__ float part[WAVES * KK * 64];   // 36864 B
    __shared__ float sig[KK * 57];            // 2052 B, padded row stride

    const int bid  = blockIdx.x;
    const int n    = bid & 7;
    const int ho   = bid >> 3;
    const int tid  = threadIdx.x;
    const int lane = tid & 63;
    const int wv   = __builtin_amdgcn_readfirstlane(tid >> 6);  // wave-uniform
    const int wo   = lane < WO ? lane : (WO - 1);               // clamp tail

    // Reflection-resolved source rows (top reflect only: -1 -> 1).
    const int r0 = (ho == 0) ? 1 : (2 * ho - 1);
    const int r1 = 2 * ho;
    const int r2 = 2 * ho + 1;

    const float* xn = x + (size_t)n * C * HW + 2 * wo;
    const int p0 = wv * PPW;   // first channel-pair of this wave

    // ---- Phase A: streamed partial sigma over the 4 channel pairs ---------
    v2f acc[KK];
#pragma unroll
    for (int k = 0; k < KK; ++k) acc[k] = (v2f){0.0f, 0.0f};

#pragma unroll 2
    for (int p = 0; p < PPW; ++p) {
        const float* xa = xn + (size_t)(2 * (p0 + p)) * HW;
        const float* xb = xa + HW;
        v2f rowa[3], rowb[3];
        rowa[0] = *(const v2f*)(xa + r0 * W);
        rowa[1] = *(const v2f*)(xa + r1 * W);
        rowa[2] = *(const v2f*)(xa + r2 * W);
        rowb[0] = *(const v2f*)(xb + r0 * W);
        rowb[1] = *(const v2f*)(xb + r1 * W);
        rowb[2] = *(const v2f*)(xb + r2 * W);
        const v2f* wb = wpk + (p0 + p) * 81;   // wave-uniform -> s_load
#pragma unroll
        for (int kh = 0; kh < 3; ++kh) {
            v2f t1 = { rowa[kh].x, rowb[kh].x };
            v2f t2 = { rowa[kh].y, rowb[kh].y };
            v2f t0;
            t0.x = __shfl_up(t2.x, 1);   // lane0 keeps own = reflect(-1)=col1
            t0.y = __shfl_up(t2.y, 1);
            const v2f* wr = wb + kh * 27;
#pragma unroll
            for (int k = 0; k < KK; ++k)
                acc[k] = pkfma(t2, wr[3 * k + 2],
                          pkfma(t1, wr[3 * k + 1],
                          pkfma(t0, wr[3 * k + 0], acc[k])));
        }
    }

#pragma unroll
    for (int k = 0; k < KK; ++k)
        part[(wv * KK + k) * 64 + lane] = acc[k].x + acc[k].y;
    __syncthreads();

    // ---- Cross-wave reduce + BN shift + clamp -----------------------------
    if (tid < KK * WO) {
        const int k  = tid / WO;
        const int w_ = tid % WO;
        float s = 0.0f;
#pragma unroll
        for (int w2 = 0; w2 < WAVES; ++w2) s += part[(w2 * KK + k) * 64 + w_];
        s += shift[k];
        s = fmaxf(s, 1e-4f);
        sig[k * 57 + w_] = s;
    }
    __syncthreads();

    // ---- Normalize into registers (per-lane, lane = wo) -------------------
    float sg[KK];
    float tot = 0.0f;
#pragma unroll
    for (int k = 0; k < KK; ++k) { sg[k] = sig[k * 57 + wo]; tot += sg[k]; }
    const float inv = 1.0f / tot;
#pragma unroll
    for (int k = 0; k < KK; ++k) sg[k] *= inv;

    // ---- Phase B: re-read x from L2, apply adaptive filter, NT store ------
    float* on = out + ((size_t)n * C) * (HO * WO) + (size_t)ho * WO + lane;
#pragma unroll 2
    for (int p = 0; p < PPW; ++p) {
        const float* xa = xn + (size_t)(2 * (p0 + p)) * HW;
        const float* xb = xa + HW;
        v2f o = (v2f){0.0f, 0.0f};
#pragma unroll
        for (int kh = 0; kh < 3; ++kh) {
            const int rr = (kh == 0) ? r0 : (kh == 1) ? r1 : r2;
            v2f a = *(const v2f*)(xa + rr * W);
            v2f b = *(const v2f*)(xb + rr * W);
            v2f t1 = { a.x, b.x };
            v2f t2 = { a.y, b.y };
            v2f t0;
            t0.x = __shfl_up(t2.x, 1);
            t0.y = __shfl_up(t2.y, 1);
            v2f s0 = { sg[kh * 3 + 0], sg[kh * 3 + 0] };
            v2f s1 = { sg[kh * 3 + 1], sg[kh * 3 + 1] };
            v2f s2 = { sg[kh * 3 + 2], sg[kh * 3 + 2] };
            o = pkfma(t2, s2, pkfma(t1, s1, pkfma(t0, s0, o)));
        }
        if (lane < WO) {
            const int ci = 2 * (p0 + p);
            __builtin_nontemporal_store(o.x, on + (size_t)ci * (HO * WO));
            __builtin_nontemporal_store(o.y, on + (size_t)(ci + 1) * (HO * WO));
        }
    }
}

extern "C" void kernel_launch(void* const* d_in, const int* in_sizes, int n_in,
                              void* d_out, int out_size, void* d_ws, size_t ws_size,
                              hipStream_t stream) {
    const float* x   = (const float*)d_in[0];
    const float* cw  = (const float*)d_in[1];
    const float* bw  = (const float*)d_in[2];
    const float* bb  = (const float*)d_in[3];
    const float* bm  = (const float*)d_in[4];
    const float* bv  = (const float*)d_in[5];
    float* ws  = (float*)d_ws;
    float* out = (float*)d_out;

    const int prep_elems = WPK_ELEMS + KK;
    pasa_prep<<<(prep_elems + 255) / 256, 256, 0, stream>>>(cw, bw, bb, bm, bv, ws);
    pasa_main<<<NB * HO, 1024, 0, stream>>>(x, (const v2f*)ws,
                                            ws + SHIFT_OFF, out);
}